// Round 13
// baseline (91.567 us; speedup 1.0000x reference)
//
#include <hip/hip_runtime.h>
#include <hip/hip_bf16.h>

// Problem: B=4, C=19, H=1024, W=1024, N=500000
// out = mean_n [ log(sum_j exp(p_j)) - p_label ],  p = softmax(predict[b,:,r,c])
//
// Round-13 = round-12 (best, 82.5us) with ONE change: TILE=512 & BLOCK=512.
//   LDS 38KB -> 4 blocks/CU x 8 waves = 32 waves/CU (SAME occupancy as R12;
//   R9's TILE=512@BLOCK=256 conflated tile size with halved occupancy).
//   Each block now stages one 2KB page-sized contiguous burst per channel
//   (vs 1KB in R12) -> tests whether DRAM page locality closes more of the
//   4.8 vs 6.3 TB/s gap in kernel A.
//
// Lessons kept: bf16 table (R12, -2.5us), NO ticket/contended atomics (R11,
// +40us!), NO mask/predication (R7/R8), NO register-array float4 (R5/R6 VGPR
// cliff), NO nontemporal hints (R5), ints arrive int32 (R1).

#define CCH 19
#define BLOCK 512
#define TILE 512                  // positions per block tile (= BLOCK)
#define POS_BITS 20               // H*W = 1<<20
#define TOTAL_POS (4 << POS_BITS) // B * H * W = 4M
#define NV4 (CCH * TILE / 4)      // 2432 float4 loads per tile
#define RBLK 256                  // block size for gather/finalize kernels

__device__ __forceinline__ float nll_compute(float* __restrict__ x, int label)
{
    float m = x[0];
    #pragma unroll
    for (int j = 1; j < CCH; ++j) m = fmaxf(m, x[j]);

    float s = 0.0f, e_label = 0.0f;
    #pragma unroll
    for (int j = 0; j < CCH; ++j) {
        float e = __expf(x[j] - m);
        s += e;
        if (j == label) e_label = e;   // static j vs runtime label -> cndmask
        x[j] = e;
    }
    float inv = 1.0f / s;

    float s2 = 0.0f;
    #pragma unroll
    for (int j = 0; j < CCH; ++j) s2 += __expf(x[j] * inv);

    return __logf(s2) - e_label * inv;
}

// ---- kernel A: LDS-tiled bf16 nll table, 38KB LDS, 32 waves/CU ----
// grid = TOTAL_POS/TILE = 8192 blocks; TILE divides H*W so a tile never
// straddles the batch dimension.
__global__ __launch_bounds__(BLOCK) void nll_table_tiled512(
    const float* __restrict__ predict,
    const int* __restrict__ target,
    __hip_bfloat16* __restrict__ table)
{
    __shared__ float lds[CCH * TILE];              // 38 KB -> 4 blocks/CU
    int i0 = blockIdx.x * TILE;                    // flat position base
    int b = i0 >> POS_BITS;
    int pos0 = i0 & ((1 << POS_BITS) - 1);
    const float* pbase = predict + (((size_t)b * CCH) << POS_BITS) + (size_t)pos0;

    // stage 19 channels x 512 floats: one 2KB contiguous float4 burst/channel
    #pragma unroll
    for (int it = 0; it < (NV4 + BLOCK - 1) / BLOCK; ++it) {
        int f = it * BLOCK + threadIdx.x;          // float4 slot in [0, 2432)
        if (f < NV4) {
            int ch = f >> 7;                       // 128 float4 per channel
            int q  = f & 127;
            float4 v = *(const float4*)(pbase + ((size_t)ch << POS_BITS) + (q << 2));
            *(float4*)&lds[ch * TILE + (q << 2)] = v;
        }
    }
    __syncthreads();

    // 1 position per thread; LDS reads lane-stride-4B (2-way aliasing = free)
    int pp = threadIdx.x;
    float x[CCH];
    #pragma unroll
    for (int j = 0; j < CCH; ++j) x[j] = lds[j * TILE + pp];
    table[i0 + pp] = __float2bfloat16(nll_compute(x, target[i0 + pp]));
}

// ---- kernel B: random 2B gather from bf16 table + block reduce ----
__global__ __launch_bounds__(RBLK) void table_gather_kernel(
    const __hip_bfloat16* __restrict__ table,
    const int* __restrict__ loc_b,
    const int* __restrict__ loc_row,
    const int* __restrict__ loc_col,
    float* __restrict__ partial,
    int n)
{
    int i = blockIdx.x * blockDim.x + threadIdx.x;
    float nll = 0.0f;
    if (i < n) {
        int idx = (loc_b[i] << POS_BITS) + (loc_row[i] << 10) + loc_col[i];
        nll = __bfloat162float(table[idx]);
    }
    __shared__ float red[RBLK];
    red[threadIdx.x] = nll;
    __syncthreads();
    #pragma unroll
    for (int off = RBLK / 2; off > 0; off >>= 1) {
        if (threadIdx.x < off) red[threadIdx.x] += red[threadIdx.x + off];
        __syncthreads();
    }
    if (threadIdx.x == 0) partial[blockIdx.x] = red[0];
}

// ---- fallback: direct random gather (round-2 path), used if ws too small ----
__global__ __launch_bounds__(RBLK) void partial_loss_gather(
    const float* __restrict__ predict,
    const int* __restrict__ target,
    const int* __restrict__ loc_b,
    const int* __restrict__ loc_row,
    const int* __restrict__ loc_col,
    float* __restrict__ partial,
    int n)
{
    int i = blockIdx.x * blockDim.x + threadIdx.x;
    float nll = 0.0f;
    if (i < n) {
        int b = loc_b[i];
        int pos = (loc_row[i] << 10) + loc_col[i];
        const float* base = predict + (((size_t)b * CCH) << POS_BITS) + (size_t)pos;
        int label = target[((size_t)b << POS_BITS) + (size_t)pos];
        float x[CCH];
        #pragma unroll
        for (int j = 0; j < CCH; ++j) x[j] = base[(size_t)j << POS_BITS];
        nll = nll_compute(x, label);
    }
    __shared__ float red[RBLK];
    red[threadIdx.x] = nll;
    __syncthreads();
    #pragma unroll
    for (int off = RBLK / 2; off > 0; off >>= 1) {
        if (threadIdx.x < off) red[threadIdx.x] += red[threadIdx.x + off];
        __syncthreads();
    }
    if (threadIdx.x == 0) partial[blockIdx.x] = red[0];
}

__global__ __launch_bounds__(RBLK) void partial_loss_finalize(
    const float* __restrict__ partial,
    int nparts,
    float* __restrict__ out,
    float inv_n)
{
    __shared__ double red[RBLK];
    double acc = 0.0;
    for (int i = threadIdx.x; i < nparts; i += RBLK) acc += (double)partial[i];
    red[threadIdx.x] = acc;
    __syncthreads();
    #pragma unroll
    for (int off = RBLK / 2; off > 0; off >>= 1) {
        if (threadIdx.x < off) red[threadIdx.x] += red[threadIdx.x + off];
        __syncthreads();
    }
    if (threadIdx.x == 0) out[0] = (float)(red[0] * (double)inv_n);
}

extern "C" void kernel_launch(void* const* d_in, const int* in_sizes, int n_in,
                              void* d_out, int out_size, void* d_ws, size_t ws_size,
                              hipStream_t stream)
{
    const float* predict = (const float*)d_in[0];
    const int*   target  = (const int*)d_in[1];
    const int*   loc_b   = (const int*)d_in[2];
    const int*   loc_row = (const int*)d_in[3];
    const int*   loc_col = (const int*)d_in[4];
    float* out = (float*)d_out;

    int n = in_sizes[2];                         // N = 500000
    int nblocks = (n + RBLK - 1) / RBLK;         // 1954

    size_t table_bytes   = (size_t)TOTAL_POS * sizeof(__hip_bfloat16);  // 8 MB
    size_t partial_bytes = (size_t)nblocks * sizeof(float);

    if (ws_size >= table_bytes + partial_bytes) {
        __hip_bfloat16* table   = (__hip_bfloat16*)d_ws;
        float*          partial = (float*)((char*)d_ws + table_bytes);

        nll_table_tiled512<<<TOTAL_POS / TILE, BLOCK, 0, stream>>>(
            predict, target, table);
        table_gather_kernel<<<nblocks, RBLK, 0, stream>>>(
            table, loc_b, loc_row, loc_col, partial, n);
        partial_loss_finalize<<<1, RBLK, 0, stream>>>(
            partial, nblocks, out, 1.0f / (float)n);
    } else {
        float* partial = (float*)d_ws;
        partial_loss_gather<<<nblocks, RBLK, 0, stream>>>(
            predict, target, loc_b, loc_row, loc_col, partial, n);
        partial_loss_finalize<<<1, RBLK, 0, stream>>>(
            partial, nblocks, out, 1.0f / (float)n);
    }
}

// Round 14
// 83.162 us; speedup vs baseline: 1.1011x; 1.1011x over previous
//
#include <hip/hip_runtime.h>
#include <hip/hip_bf16.h>

// Problem: B=4, C=19, H=1024, W=1024, N=500000
// out = mean_n [ log(sum_j exp(p_j)) - p_label ],  p = softmax(predict[b,:,r,c])
//
// FINAL (= round-12, session best 82.5us):
//   (A) LDS-tiled streaming pass, TILE=256/BLOCK=256 (19KB LDS, 8 blocks/CU
//       = 32 waves/CU): stages 19 channels x 256 pos as one 1KB contiguous
//       float4 burst per channel, computes nll for all 4M positions into an
//       8MB bf16 table in d_ws.
//   (B) random 2B gather from table + block tree-reduce -> partials.
//   (C) finalize: fixed-order double accumulation -> mean.
//
// Tested-and-rejected (this session): 2KB bursts / BLOCK=512 (R13 +9us,
// coarser barriers), ticket-fused finalize (R11 +42us, contended atomics),
// count-table atomic scatter (R8 +25us), chunk-mask predication (R7 neutral:
// build cost = savings), register float4 (R5/R6 +7-9us, VGPR/occupancy
// cliff), nontemporal hints (R5). Byte floor: A = 328MB mixed-stream at
// ~4.8-5 TB/s (mixed R/W ceiling) ~= 66-69us; total structural floor
// ~74-79us -> 82.5 is within ~5-10%.
//
// NOTE: harness ABI passes ALL integer inputs as int32.

#define CCH 19
#define BLOCK 256
#define TILE 256                  // positions per block tile (= BLOCK)
#define POS_BITS 20               // H*W = 1<<20
#define TOTAL_POS (4 << POS_BITS) // B * H * W = 4M
#define NV4 (CCH * TILE / 4)      // 1216 float4 loads per tile

__device__ __forceinline__ float nll_compute(float* __restrict__ x, int label)
{
    float m = x[0];
    #pragma unroll
    for (int j = 1; j < CCH; ++j) m = fmaxf(m, x[j]);

    float s = 0.0f, e_label = 0.0f;
    #pragma unroll
    for (int j = 0; j < CCH; ++j) {
        float e = __expf(x[j] - m);
        s += e;
        if (j == label) e_label = e;   // static j vs runtime label -> cndmask
        x[j] = e;
    }
    float inv = 1.0f / s;

    float s2 = 0.0f;
    #pragma unroll
    for (int j = 0; j < CCH; ++j) s2 += __expf(x[j] * inv);

    return __logf(s2) - e_label * inv;
}

// ---- kernel A: LDS-tiled bf16 nll table, 19KB LDS, full occupancy ----
__global__ __launch_bounds__(BLOCK) void nll_table_tiled256(
    const float* __restrict__ predict,
    const int* __restrict__ target,
    __hip_bfloat16* __restrict__ table)
{
    __shared__ float lds[CCH * TILE];              // 19 KB -> 8 blocks/CU
    int i0 = blockIdx.x * TILE;                    // flat position base
    int b = i0 >> POS_BITS;
    int pos0 = i0 & ((1 << POS_BITS) - 1);
    const float* pbase = predict + (((size_t)b * CCH) << POS_BITS) + (size_t)pos0;

    // stage 19 channels x 256 floats: one 1KB contiguous float4 burst/channel
    #pragma unroll
    for (int it = 0; it < (NV4 + BLOCK - 1) / BLOCK; ++it) {
        int f = it * BLOCK + threadIdx.x;          // float4 slot in [0, 1216)
        if (f < NV4) {
            int ch = f >> 6;                       // 64 float4 per channel
            int q  = f & 63;
            float4 v = *(const float4*)(pbase + ((size_t)ch << POS_BITS) + (q << 2));
            *(float4*)&lds[ch * TILE + (q << 2)] = v;
        }
    }
    __syncthreads();

    // 1 position per thread; LDS reads lane-stride-4B (2-way aliasing = free)
    int pp = threadIdx.x;
    float x[CCH];
    #pragma unroll
    for (int j = 0; j < CCH; ++j) x[j] = lds[j * TILE + pp];
    table[i0 + pp] = __float2bfloat16(nll_compute(x, target[i0 + pp]));
}

// ---- kernel B: random 2B gather from bf16 table + block reduce ----
__global__ __launch_bounds__(BLOCK) void table_gather_kernel(
    const __hip_bfloat16* __restrict__ table,
    const int* __restrict__ loc_b,
    const int* __restrict__ loc_row,
    const int* __restrict__ loc_col,
    float* __restrict__ partial,
    int n)
{
    int i = blockIdx.x * blockDim.x + threadIdx.x;
    float nll = 0.0f;
    if (i < n) {
        int idx = (loc_b[i] << POS_BITS) + (loc_row[i] << 10) + loc_col[i];
        nll = __bfloat162float(table[idx]);
    }
    __shared__ float red[BLOCK];
    red[threadIdx.x] = nll;
    __syncthreads();
    #pragma unroll
    for (int off = BLOCK / 2; off > 0; off >>= 1) {
        if (threadIdx.x < off) red[threadIdx.x] += red[threadIdx.x + off];
        __syncthreads();
    }
    if (threadIdx.x == 0) partial[blockIdx.x] = red[0];
}

// ---- fallback: direct random gather (round-2 path), used if ws too small ----
__global__ __launch_bounds__(BLOCK) void partial_loss_gather(
    const float* __restrict__ predict,
    const int* __restrict__ target,
    const int* __restrict__ loc_b,
    const int* __restrict__ loc_row,
    const int* __restrict__ loc_col,
    float* __restrict__ partial,
    int n)
{
    int i = blockIdx.x * blockDim.x + threadIdx.x;
    float nll = 0.0f;
    if (i < n) {
        int b = loc_b[i];
        int pos = (loc_row[i] << 10) + loc_col[i];
        const float* base = predict + (((size_t)b * CCH) << POS_BITS) + (size_t)pos;
        int label = target[((size_t)b << POS_BITS) + (size_t)pos];
        float x[CCH];
        #pragma unroll
        for (int j = 0; j < CCH; ++j) x[j] = base[(size_t)j << POS_BITS];
        nll = nll_compute(x, label);
    }
    __shared__ float red[BLOCK];
    red[threadIdx.x] = nll;
    __syncthreads();
    #pragma unroll
    for (int off = BLOCK / 2; off > 0; off >>= 1) {
        if (threadIdx.x < off) red[threadIdx.x] += red[threadIdx.x + off];
        __syncthreads();
    }
    if (threadIdx.x == 0) partial[blockIdx.x] = red[0];
}

__global__ __launch_bounds__(BLOCK) void partial_loss_finalize(
    const float* __restrict__ partial,
    int nparts,
    float* __restrict__ out,
    float inv_n)
{
    __shared__ double red[BLOCK];
    double acc = 0.0;
    for (int i = threadIdx.x; i < nparts; i += BLOCK) acc += (double)partial[i];
    red[threadIdx.x] = acc;
    __syncthreads();
    #pragma unroll
    for (int off = BLOCK / 2; off > 0; off >>= 1) {
        if (threadIdx.x < off) red[threadIdx.x] += red[threadIdx.x + off];
        __syncthreads();
    }
    if (threadIdx.x == 0) out[0] = (float)(red[0] * (double)inv_n);
}

extern "C" void kernel_launch(void* const* d_in, const int* in_sizes, int n_in,
                              void* d_out, int out_size, void* d_ws, size_t ws_size,
                              hipStream_t stream)
{
    const float* predict = (const float*)d_in[0];
    const int*   target  = (const int*)d_in[1];
    const int*   loc_b   = (const int*)d_in[2];
    const int*   loc_row = (const int*)d_in[3];
    const int*   loc_col = (const int*)d_in[4];
    float* out = (float*)d_out;

    int n = in_sizes[2];                         // N = 500000
    int nblocks = (n + BLOCK - 1) / BLOCK;       // 1954

    size_t table_bytes   = (size_t)TOTAL_POS * sizeof(__hip_bfloat16);  // 8 MB
    size_t partial_bytes = (size_t)nblocks * sizeof(float);

    if (ws_size >= table_bytes + partial_bytes) {
        __hip_bfloat16* table   = (__hip_bfloat16*)d_ws;
        float*          partial = (float*)((char*)d_ws + table_bytes);

        nll_table_tiled256<<<TOTAL_POS / TILE, BLOCK, 0, stream>>>(
            predict, target, table);
        table_gather_kernel<<<nblocks, BLOCK, 0, stream>>>(
            table, loc_b, loc_row, loc_col, partial, n);
        partial_loss_finalize<<<1, BLOCK, 0, stream>>>(
            partial, nblocks, out, 1.0f / (float)n);
    } else {
        float* partial = (float*)d_ws;
        partial_loss_gather<<<nblocks, BLOCK, 0, stream>>>(
            predict, target, loc_b, loc_row, loc_col, partial, n);
        partial_loss_finalize<<<1, BLOCK, 0, stream>>>(
            partial, nblocks, out, 1.0f / (float)n);
    }
}